// Round 3
// baseline (921.463 us; speedup 1.0000x reference)
//
#include <hip/hip_runtime.h>
#include <hip/hip_bf16.h>

typedef __bf16 bf16_t;
typedef __attribute__((ext_vector_type(8))) __bf16 bf16x8;
typedef __attribute__((ext_vector_type(4))) float f32x4;

constexpr int IN_F  = 4096;   // K (reduction)
constexpr int OUT_F = 16384;  // weight rows
constexpr int N_TOK = 8192;   // M
constexpr int KSEL  = 8192;   // N (kept rows = OUT_F/2)

constexpr int BM = 128, BN = 128, BK = 64;
constexpr long A_ELEMS = (long)N_TOK * IN_F;   // 33.5M (also = KSEL*IN_F)

#define GLOBAL_CAST(p) (const __attribute__((address_space(1))) void*)(p)
#define LDS_CAST(p)    (__attribute__((address_space(3))) void*)(p)

// ---------------------------------------------------------------------------
// Kernel 1: idx[] = positions of mask==1 (ascending) + gather bias (fp32).
// ---------------------------------------------------------------------------
__global__ __launch_bounds__(1024) void build_idx_kernel(
    const int* __restrict__ mask, const float* __restrict__ bias,
    int* __restrict__ idx, float* __restrict__ bsel)
{
    const int t    = threadIdx.x;      // 0..1023
    const int lane = t & 63;
    const int wave = t >> 6;           // 0..15
    const int base_i = t * 16;

    int m[16];
    const int4* mp = (const int4*)(mask + base_i);
#pragma unroll
    for (int v = 0; v < 4; ++v) {
        int4 q = mp[v];
        m[v*4+0] = q.x; m[v*4+1] = q.y; m[v*4+2] = q.z; m[v*4+3] = q.w;
    }
    int cnt = 0;
#pragma unroll
    for (int j = 0; j < 16; ++j) cnt += (m[j] != 0) ? 1 : 0;

    int incl = cnt;
#pragma unroll
    for (int d = 1; d < 64; d <<= 1) {
        int o = __shfl_up(incl, (unsigned)d);
        if (lane >= d) incl += o;
    }

    __shared__ int wsum[16];
    __shared__ int wbase[16];
    if (lane == 63) wsum[wave] = incl;
    __syncthreads();
    if (t == 0) {
        int s = 0;
        for (int w = 0; w < 16; ++w) { wbase[w] = s; s += wsum[w]; }
    }
    __syncthreads();

    int p = wbase[wave] + (incl - cnt);
#pragma unroll
    for (int j = 0; j < 16; ++j) {
        if (m[j]) {
            int i = base_i + j;
            idx[p]  = i;
            bsel[p] = bias[i];
            ++p;
        }
    }
}

// ---------------------------------------------------------------------------
// Kernel 2 (fast path): fp32 -> bf16 convert; A straight, W gathered by idx.
// ---------------------------------------------------------------------------
__global__ __launch_bounds__(256) void convert_kernel(
    const float* __restrict__ A, const float* __restrict__ W,
    const int* __restrict__ idx,
    bf16_t* __restrict__ Ab, bf16_t* __restrict__ Wb)
{
    const long nvecA = A_ELEMS / 8;
    const long total = nvecA * 2;
    const long stride = (long)gridDim.x * blockDim.x;
    for (long v = (long)blockIdx.x * blockDim.x + threadIdx.x; v < total; v += stride) {
        const float4* src;
        bf16_t* dst;
        if (v < nvecA) {
            src = (const float4*)(A + v * 8);
            dst = Ab + v * 8;
        } else {
            long u = v - nvecA;
            int j = (int)(u >> 9);            // 512 x 8-elem vectors per row
            int k = (int)(u & 511) * 8;
            src = (const float4*)(W + (long)idx[j] * IN_F + k);
            dst = Wb + u * 8;
        }
        float4 x = src[0], y = src[1];
        bf16x8 o;
        o[0]=(bf16_t)x.x; o[1]=(bf16_t)x.y; o[2]=(bf16_t)x.z; o[3]=(bf16_t)x.w;
        o[4]=(bf16_t)y.x; o[5]=(bf16_t)y.y; o[6]=(bf16_t)y.z; o[7]=(bf16_t)y.w;
        *(bf16x8*)dst = o;
    }
}

// ---------------------------------------------------------------------------
// Kernel 3 (fast path): C[M,N] = Ab[M,K] * Wb[N,K]^T + bsel[N]; fp32 out.
// m97-structure: 128x128 tile, BK=64, 4 waves (2x2), 16x16x32 bf16 MFMA,
// global_load_lds width=16 staging.
// ---------------------------------------------------------------------------
__global__ __launch_bounds__(256) void gemm_bf16_kernel(
    const bf16_t* __restrict__ A, const bf16_t* __restrict__ B,
    const float* __restrict__ bsel, float* __restrict__ C)
{
    __shared__ __attribute__((aligned(16))) bf16_t As[BM * BK];
    __shared__ __attribute__((aligned(16))) bf16_t Bs[BN * BK];

    const int tid  = threadIdx.x;
    const int wave = tid >> 6;
    const int lane = tid & 63;
    const int wr   = wave >> 1;
    const int wc   = wave & 1;

    const int m0 = blockIdx.x * BM;
    const int n0 = blockIdx.y * BN;

    const int srow = lane >> 3;         // 8 rows per issue (row = 128 B)
    const int scol = (lane & 7) * 8;    // bf16 elems

    const bf16_t* aptr[4];
    const bf16_t* bptr[4];
#pragma unroll
    for (int i = 0; i < 4; ++i) {
        aptr[i] = A + (long)(m0 + wave * 32 + i * 8 + srow) * IN_F + scol;
        bptr[i] = B + (long)(n0 + wave * 32 + i * 8 + srow) * IN_F + scol;
    }

    f32x4 acc[4][4];
#pragma unroll
    for (int m = 0; m < 4; ++m)
#pragma unroll
        for (int n = 0; n < 4; ++n)
#pragma unroll
            for (int j = 0; j < 4; ++j) acc[m][n][j] = 0.f;

    const int fr = lane & 15;
    const int fk = (lane >> 4) * 8;

    for (int k0 = 0; k0 < IN_F; k0 += BK) {
#pragma unroll
        for (int i = 0; i < 4; ++i) {
            __builtin_amdgcn_global_load_lds(GLOBAL_CAST(aptr[i] + k0),
                LDS_CAST(&As[(wave * 32 + i * 8) * BK]), 16, 0, 0);
            __builtin_amdgcn_global_load_lds(GLOBAL_CAST(bptr[i] + k0),
                LDS_CAST(&Bs[(wave * 32 + i * 8) * BK]), 16, 0, 0);
        }
        __syncthreads();

#pragma unroll
        for (int kk = 0; kk < BK; kk += 32) {
            bf16x8 af[4], bg[4];
#pragma unroll
            for (int m = 0; m < 4; ++m)
                af[m] = *(const bf16x8*)&As[(wr * 64 + m * 16 + fr) * BK + kk + fk];
#pragma unroll
            for (int n = 0; n < 4; ++n)
                bg[n] = *(const bf16x8*)&Bs[(wc * 64 + n * 16 + fr) * BK + kk + fk];
#pragma unroll
            for (int m = 0; m < 4; ++m)
#pragma unroll
                for (int n = 0; n < 4; ++n)
                    acc[m][n] = __builtin_amdgcn_mfma_f32_16x16x32_bf16(
                        af[m], bg[n], acc[m][n], 0, 0, 0);
        }
        __syncthreads();
    }

    float b4[4];
#pragma unroll
    for (int n = 0; n < 4; ++n) b4[n] = bsel[n0 + wc * 64 + n * 16 + fr];

    const int rbase = m0 + wr * 64 + (lane >> 4) * 4;
#pragma unroll
    for (int m = 0; m < 4; ++m)
#pragma unroll
        for (int n = 0; n < 4; ++n) {
            const int col = n0 + wc * 64 + n * 16 + fr;
#pragma unroll
            for (int j = 0; j < 4; ++j)
                C[(long)(rbase + m * 16 + j) * KSEL + col] = acc[m][n][j] + b4[n];
        }
}

// ---------------------------------------------------------------------------
// Kernel 3' (fallback, ws too small): stage fp32 tiles via global_load_lds
// (BK=32, 32 KB LDS), convert to bf16 on ds_read, same MFMA core.
// ---------------------------------------------------------------------------
__global__ __launch_bounds__(256) void gemm_f32staged_kernel(
    const float* __restrict__ A, const float* __restrict__ W,
    const int* __restrict__ idx, const float* __restrict__ bsel,
    float* __restrict__ C)
{
    constexpr int BK2 = 32;
    __shared__ __attribute__((aligned(16))) float Asf[BM * BK2];
    __shared__ __attribute__((aligned(16))) float Bsf[BN * BK2];

    const int tid  = threadIdx.x;
    const int wave = tid >> 6;
    const int lane = tid & 63;
    const int wr   = wave >> 1;
    const int wc   = wave & 1;

    const int m0 = blockIdx.x * BM;
    const int n0 = blockIdx.y * BN;

    const int srow = lane >> 3;         // row = 32 floats = 128 B; 8 rows/issue
    const int scol = (lane & 7) * 4;    // float elems

    const float* aptr[4];
    const float* bptr[4];
#pragma unroll
    for (int i = 0; i < 4; ++i) {
        aptr[i] = A + (long)(m0 + wave * 32 + i * 8 + srow) * IN_F + scol;
        const int br = idx[n0 + wave * 32 + i * 8 + srow];
        bptr[i] = W + (long)br * IN_F + scol;
    }

    f32x4 acc[4][4];
#pragma unroll
    for (int m = 0; m < 4; ++m)
#pragma unroll
        for (int n = 0; n < 4; ++n)
#pragma unroll
            for (int j = 0; j < 4; ++j) acc[m][n][j] = 0.f;

    const int fr = lane & 15;
    const int fk = (lane >> 4) * 8;

    for (int k0 = 0; k0 < IN_F; k0 += BK2) {
#pragma unroll
        for (int i = 0; i < 4; ++i) {
            __builtin_amdgcn_global_load_lds(GLOBAL_CAST(aptr[i] + k0),
                LDS_CAST(&Asf[(wave * 32 + i * 8) * BK2]), 16, 0, 0);
            __builtin_amdgcn_global_load_lds(GLOBAL_CAST(bptr[i] + k0),
                LDS_CAST(&Bsf[(wave * 32 + i * 8) * BK2]), 16, 0, 0);
        }
        __syncthreads();

        bf16x8 af[4], bg[4];
#pragma unroll
        for (int m = 0; m < 4; ++m) {
            const float* p = &Asf[(wr * 64 + m * 16 + fr) * BK2 + fk];
            f32x4 x = *(const f32x4*)p, y = *(const f32x4*)(p + 4);
#pragma unroll
            for (int j = 0; j < 4; ++j) { af[m][j] = (bf16_t)x[j]; af[m][4+j] = (bf16_t)y[j]; }
        }
#pragma unroll
        for (int n = 0; n < 4; ++n) {
            const float* p = &Bsf[(wc * 64 + n * 16 + fr) * BK2 + fk];
            f32x4 x = *(const f32x4*)p, y = *(const f32x4*)(p + 4);
#pragma unroll
            for (int j = 0; j < 4; ++j) { bg[n][j] = (bf16_t)x[j]; bg[n][4+j] = (bf16_t)y[j]; }
        }
#pragma unroll
        for (int m = 0; m < 4; ++m)
#pragma unroll
            for (int n = 0; n < 4; ++n)
                acc[m][n] = __builtin_amdgcn_mfma_f32_16x16x32_bf16(
                    af[m], bg[n], acc[m][n], 0, 0, 0);
        __syncthreads();
    }

    float b4[4];
#pragma unroll
    for (int n = 0; n < 4; ++n) b4[n] = bsel[n0 + wc * 64 + n * 16 + fr];

    const int rbase = m0 + wr * 64 + (lane >> 4) * 4;
#pragma unroll
    for (int m = 0; m < 4; ++m)
#pragma unroll
        for (int n = 0; n < 4; ++n) {
            const int col = n0 + wc * 64 + n * 16 + fr;
#pragma unroll
            for (int j = 0; j < 4; ++j)
                C[(long)(rbase + m * 16 + j) * KSEL + col] = acc[m][n][j] + b4[n];
        }
}

// ---------------------------------------------------------------------------
extern "C" void kernel_launch(void* const* d_in, const int* in_sizes, int n_in,
                              void* d_out, int out_size, void* d_ws, size_t ws_size,
                              hipStream_t stream)
{
    const float* data   = (const float*)d_in[0];  // [N_TOK, IN_F]
    const float* weight = (const float*)d_in[1];  // [OUT_F, IN_F]
    const float* bias   = (const float*)d_in[2];  // [OUT_F]
    const int*   mask   = (const int*)d_in[3];    // [OUT_F]
    float*       out    = (float*)d_out;          // [N_TOK, KSEL]

    char* ws = (char*)d_ws;
    int*   idx  = (int*)ws;                         // 32 KB
    float* bsel = (float*)(ws + (KSEL * 4));        // 32 KB
    bf16_t* Ab  = (bf16_t*)(ws + (KSEL * 8));       // 64 MiB
    bf16_t* Wb  = Ab + A_ELEMS;                     // 64 MiB

    const size_t NEED = (size_t)KSEL * 8 + (size_t)A_ELEMS * 2 * 2;

    build_idx_kernel<<<1, 1024, 0, stream>>>(mask, bias, idx, bsel);

    dim3 grid(N_TOK / BM, KSEL / BN);
    if (ws_size >= NEED) {
        convert_kernel<<<2048, 256, 0, stream>>>(data, weight, idx, Ab, Wb);
        gemm_bf16_kernel<<<grid, 256, 0, stream>>>(Ab, Wb, bsel, out);
    } else {
        gemm_f32staged_kernel<<<grid, 256, 0, stream>>>(data, weight, idx, bsel, out);
    }
}